// Round 9
// baseline (18959.459 us; speedup 1.0000x reference)
//
#include <hip/hip_runtime.h>
#include <math.h>

#define BLOCK 256
#define PPB 64     // problems per block (16 per wave)
#define HP 132     // floats per problem h-column (128 + 4 pad; 528B = 33*16, float4-aligned)

typedef float v2f __attribute__((ext_vector_type(2)));

__device__ __forceinline__ v2f mkv2(float a, float b) {
    v2f r; r.x = a; r.y = b; return r;
}
__device__ __forceinline__ v2f pkfma(v2f a, v2f b, v2f c) {
#if __has_builtin(__builtin_elementwise_fma)
    return __builtin_elementwise_fma(a, b, c);
#else
    return mkv2(fmaf(a.x, b.x, c.x), fmaf(a.y, b.y, c.y));
#endif
}
__device__ __forceinline__ float f4el(const float4& v, int r) {
    return (r == 0) ? v.x : (r == 1) ? v.y : (r == 2) ? v.z : v.w;
}

// prep: W0 [27][128] -> W0p [32][128] (zero rows); W4 [128][25] -> W4p [128][32]
// (zero cols); b4 [25] -> b4p [32]
__global__ void prep_kernel(const float* __restrict__ W0, const float* __restrict__ W4,
                            const float* __restrict__ b4, float* __restrict__ W0p,
                            float* __restrict__ W4p, float* __restrict__ b4p) {
    const int t = blockIdx.x * blockDim.x + threadIdx.x;
    if (t < 32 * 128) {
        const int k = t >> 7, j = t & 127;
        W0p[t] = (k < 27) ? W0[k * 128 + j] : 0.0f;
    }
    if (t < 128 * 32) {
        const int k = t >> 5, j = t & 31;
        W4p[t] = (j < 25) ? W4[k * 25 + j] : 0.0f;
    }
    if (t < 32) b4p[t] = (t < 25) ? b4[t] : 0.0f;
}

// main layer: lane owns 8 cols x 4 probs. Wc = W + 8*cg (row stride WS),
// bc = b + 8*cg, hg = h base of prob group (4*gg), hwr = hg + 8*cg.
// 4-row batches, double-buffered weights (WA/WB) and h (hA/hB as float4).
// NOTE: h pointers intentionally NOT __restrict__ (same buffer; lockstep wave
// ordering makes read-then-write safe).
template <int K, int WS>
__device__ __forceinline__ void layerM(const float* __restrict__ Wc,
                                       const float* __restrict__ bc,
                                       const float* hg, float* hwr) {
    constexpr int NB = K / 4;  // batches of 4 rows; 8 or 32 (even)
    v2f acc[16];
    {
        const float4 b0 = *(const float4*)(bc);
        const float4 b1 = *(const float4*)(bc + 4);
#pragma unroll
        for (int p = 0; p < 4; ++p) {
            acc[p * 4 + 0] = mkv2(b0.x, b0.y);
            acc[p * 4 + 1] = mkv2(b0.z, b0.w);
            acc[p * 4 + 2] = mkv2(b1.x, b1.y);
            acc[p * 4 + 3] = mkv2(b1.z, b1.w);
        }
    }
    float4 WA[8], WB[8], hA[4], hB[4];
    // prologue: batch 0 -> A
#pragma unroll
    for (int r = 0; r < 4; ++r) {
        WA[r * 2 + 0] = *(const float4*)(Wc + r * WS);
        WA[r * 2 + 1] = *(const float4*)(Wc + r * WS + 4);
    }
#pragma unroll
    for (int p = 0; p < 4; ++p) hA[p] = *(const float4*)(hg + p * HP);
    for (int b = 0; b < NB; b += 2) {
        // issue batch b+1 -> B
        {
            const float* Wn = Wc + (b + 1) * 4 * WS;
            const float* hn = hg + (b + 1) * 4;
#pragma unroll
            for (int r = 0; r < 4; ++r) {
                WB[r * 2 + 0] = *(const float4*)(Wn + r * WS);
                WB[r * 2 + 1] = *(const float4*)(Wn + r * WS + 4);
            }
#pragma unroll
            for (int p = 0; p < 4; ++p) hB[p] = *(const float4*)(hn + p * HP);
        }
        // FMA batch A
#pragma unroll
        for (int r = 0; r < 4; ++r) {
            const v2f wa = mkv2(WA[r * 2 + 0].x, WA[r * 2 + 0].y);
            const v2f wb = mkv2(WA[r * 2 + 0].z, WA[r * 2 + 0].w);
            const v2f wc = mkv2(WA[r * 2 + 1].x, WA[r * 2 + 1].y);
            const v2f wd = mkv2(WA[r * 2 + 1].z, WA[r * 2 + 1].w);
#pragma unroll
            for (int p = 0; p < 4; ++p) {
                const float hv = f4el(hA[p], r);
                const v2f hh = mkv2(hv, hv);
                acc[p * 4 + 0] = pkfma(hh, wa, acc[p * 4 + 0]);
                acc[p * 4 + 1] = pkfma(hh, wb, acc[p * 4 + 1]);
                acc[p * 4 + 2] = pkfma(hh, wc, acc[p * 4 + 2]);
                acc[p * 4 + 3] = pkfma(hh, wd, acc[p * 4 + 3]);
            }
        }
        // issue batch b+2 -> A (clamped redundant reload on the last iteration)
        {
            const int bn = (b + 2 < NB) ? (b + 2) : (NB - 2);
            const float* Wn = Wc + bn * 4 * WS;
            const float* hn = hg + bn * 4;
#pragma unroll
            for (int r = 0; r < 4; ++r) {
                WA[r * 2 + 0] = *(const float4*)(Wn + r * WS);
                WA[r * 2 + 1] = *(const float4*)(Wn + r * WS + 4);
            }
#pragma unroll
            for (int p = 0; p < 4; ++p) hA[p] = *(const float4*)(hn + p * HP);
        }
        // FMA batch B
#pragma unroll
        for (int r = 0; r < 4; ++r) {
            const v2f wa = mkv2(WB[r * 2 + 0].x, WB[r * 2 + 0].y);
            const v2f wb = mkv2(WB[r * 2 + 0].z, WB[r * 2 + 0].w);
            const v2f wc = mkv2(WB[r * 2 + 1].x, WB[r * 2 + 1].y);
            const v2f wd = mkv2(WB[r * 2 + 1].z, WB[r * 2 + 1].w);
#pragma unroll
            for (int p = 0; p < 4; ++p) {
                const float hv = f4el(hB[p], r);
                const v2f hh = mkv2(hv, hv);
                acc[p * 4 + 0] = pkfma(hh, wa, acc[p * 4 + 0]);
                acc[p * 4 + 1] = pkfma(hh, wb, acc[p * 4 + 1]);
                acc[p * 4 + 2] = pkfma(hh, wc, acc[p * 4 + 2]);
                acc[p * 4 + 3] = pkfma(hh, wd, acc[p * 4 + 3]);
            }
        }
    }
#pragma unroll
    for (int p = 0; p < 4; ++p) {
        float4 o0, o1;
        o0.x = fmaxf(acc[p * 4 + 0].x, 0.f); o0.y = fmaxf(acc[p * 4 + 0].y, 0.f);
        o0.z = fmaxf(acc[p * 4 + 1].x, 0.f); o0.w = fmaxf(acc[p * 4 + 1].y, 0.f);
        o1.x = fmaxf(acc[p * 4 + 2].x, 0.f); o1.y = fmaxf(acc[p * 4 + 2].y, 0.f);
        o1.z = fmaxf(acc[p * 4 + 3].x, 0.f); o1.w = fmaxf(acc[p * 4 + 3].y, 0.f);
        *(float4*)(hwr + p * HP) = o0;
        *(float4*)(hwr + p * HP + 4) = o1;
    }
}

__global__ __launch_bounds__(BLOCK)
__attribute__((amdgpu_num_vgpr(168))) void snarf_kernel(
    const float* __restrict__ xin, const float* __restrict__ bone_pts,
    const float* __restrict__ transforms, const float* __restrict__ delta_tf,
    const float* __restrict__ W0p, const float* __restrict__ b0,
    const float* __restrict__ W1, const float* __restrict__ b1,
    const float* __restrict__ W2, const float* __restrict__ b2,
    const float* __restrict__ W3, const float* __restrict__ b3,
    const float* __restrict__ W4p, const float* __restrict__ b4p,
    float* __restrict__ out, int Npts) {
    __shared__ float hL[PPB * HP];      // 33792 B, h[prob][k]
    __shared__ float stL[22 * PPB];     // 5632 B solver state  (total 39424 B)
    const int tid = threadIdx.x;
    const int wid = tid >> 6;
    const int lane = tid & 63;
    const int p16 = lane & 15;   // my prob (epilogue/pe/last-layer mapping)
    const int sq = lane >> 4;    // duplicate group 0..3
    const int cg = lane >> 2;    // main-layer col group 0..15 (8 cols)
    const int gg = lane & 3;     // main-layer prob group 0..3 (4 probs)
    const int M = Npts * 6;
    const int m = blockIdx.x * PPB + wid * 16 + p16;
    const int mc = (m < M) ? m : (M - 1);
    const int n = mc / 6;
    const int i = mc - n * 6;

    float* hWv = &hL[wid * 16 * HP];          // wave's 16 prob columns
    const float* hg = hWv + (4 * gg) * HP;    // k-loop read base (4 probs)
    float* hwr = hWv + (4 * gg) * HP + 8 * cg;
    float* hq = hWv + p16 * HP;               // my prob's column
    volatile float* st = &stL[wid * 16 + p16];
#define STS(idx) st[(idx) * PPB]

    const float tx = xin[n * 3 + 0], ty = xin[n * 3 + 1], tz = xin[n * 3 + 2];

    // ---- init candidate (duplicated across sq; bitwise identical)
    float xk0, xk1, xk2;
    if (i < 5) {
        float dprev = -1.0f;
        int jprev = -1;
        for (int r = 0; r <= i; ++r) {
            float bd = 3.4028235e38f;
            int bj = 0;
            for (int j = 0; j < 24; ++j) {
                const float ax = tx - bone_pts[j * 3 + 0];
                const float ay = ty - bone_pts[j * 3 + 1];
                const float az = tz - bone_pts[j * 3 + 2];
                const float d = sqrtf(ax * ax + ay * ay + az * az);
                const bool taken = (d < dprev) || (d == dprev && j <= jprev);
                if (!taken && d < bd) { bd = d; bj = j; }
            }
            dprev = bd;
            jprev = bj;
        }
        const float* T = delta_tf + jprev * 16;
        xk0 = fmaf(T[0], tx, fmaf(T[1], ty, fmaf(T[2], tz, T[3])));
        xk1 = fmaf(T[4], tx, fmaf(T[5], ty, fmaf(T[6], tz, T[7])));
        xk2 = fmaf(T[8], tx, fmaf(T[9], ty, fmaf(T[10], tz, T[11])));
    } else {
        xk0 = tx; xk1 = ty; xk2 = tz;
    }

    float gx0 = 0.f, gx1 = 0.f, gx2 = 0.f;
    bool mask = (m < M);

    int step = -1;  // -1 init eval, 0..7 Broyden, 8 final eval
    while (step <= 8) {
        bool m3 = mask;
        if (step >= 0 && step < 8) {
            if (__ballot(mask) == 0ull) { step = 8; continue; }  // wave-local exit
            if (m3) {
                const float u0 = STS(9), u1 = STS(10), u2 = STS(11);
                STS(12) = u0; STS(13) = u1; STS(14) = u2;  // dx = up
                xk0 += u0; xk1 += u1; xk2 += u2;
            }
        }
        float cx0 = xk0, cx1 = xk1, cx2 = xk2;
        if (step == 8) { cx0 = STS(18); cx1 = STS(19); cx2 = STS(20); }

        // ---- positional encoding: all 12 sincos (dup x4); sq writes its 8 rows
        float s1x, c1x, s1y, c1y, s1z, c1z;
        float s2x, c2x, s2y, c2y, s2z, c2z;
        float s4x, c4x, s4y, c4y, s4z, c4z;
        float s8x, c8x, s8y, c8y, s8z, c8z;
        sincosf(cx0, &s1x, &c1x); sincosf(cx1, &s1y, &c1y); sincosf(cx2, &s1z, &c1z);
        sincosf(2.f * cx0, &s2x, &c2x); sincosf(2.f * cx1, &s2y, &c2y); sincosf(2.f * cx2, &s2z, &c2z);
        sincosf(4.f * cx0, &s4x, &c4x); sincosf(4.f * cx1, &s4y, &c4y); sincosf(4.f * cx2, &s4z, &c4z);
        sincosf(8.f * cx0, &s8x, &c8x); sincosf(8.f * cx1, &s8y, &c8y); sincosf(8.f * cx2, &s8z, &c8z);
        {
            float4 a, b;
            if (sq == 0) {
                a.x = cx0; a.y = cx1; a.z = cx2; a.w = s1x;
                b.x = s1y; b.y = s1z; b.z = s2x; b.w = s2y;
            } else if (sq == 1) {
                a.x = s2z; a.y = s4x; a.z = s4y; a.w = s4z;
                b.x = s8x; b.y = s8y; b.z = s8z; b.w = c1x;
            } else if (sq == 2) {
                a.x = c1y; a.y = c1z; a.z = c2x; a.w = c2y;
                b.x = c2z; b.y = c4x; b.z = c4y; b.w = c4z;
            } else {
                a.x = c8x; a.y = c8y; a.z = c8z; a.w = 0.f;
                b.x = 0.f; b.y = 0.f; b.z = 0.f; b.w = 0.f;
            }
            *(float4*)(hq + sq * 8) = a;
            *(float4*)(hq + sq * 8 + 4) = b;
        }

        layerM<32, 128>(W0p + 8 * cg, b0 + 8 * cg, hg, hwr);
        layerM<128, 128>(W1 + 8 * cg, b1 + 8 * cg, hg, hwr);
        layerM<128, 128>(W2 + 8 * cg, b2 + 8 * cg, hg, hwr);
        layerM<128, 128>(W3 + 8 * cg, b3 + 8 * cg, hg, hwr);

        // ---- output layer: lane (sq, p16) computes cols 8sq..8sq+8 of prob p16
        {
            v2f la[4];
            const float* bc = b4p + 8 * sq;
            const float4 bb0 = *(const float4*)(bc);
            const float4 bb1 = *(const float4*)(bc + 4);
            la[0] = mkv2(bb0.x, bb0.y); la[1] = mkv2(bb0.z, bb0.w);
            la[2] = mkv2(bb1.x, bb1.y); la[3] = mkv2(bb1.z, bb1.w);
            const float* Wc = W4p + 8 * sq;
#pragma unroll 2
            for (int kb = 0; kb < 32; ++kb) {
                const float4 h4 = *(const float4*)(hq + kb * 4);
#pragma unroll
                for (int r = 0; r < 4; ++r) {
                    const int k = kb * 4 + r;
                    const float4 w0 = *(const float4*)(Wc + k * 32);
                    const float4 w1 = *(const float4*)(Wc + k * 32 + 4);
                    const float hv = f4el(h4, r);
                    const v2f hh = mkv2(hv, hv);
                    la[0] = pkfma(hh, mkv2(w0.x, w0.y), la[0]);
                    la[1] = pkfma(hh, mkv2(w0.z, w0.w), la[1]);
                    la[2] = pkfma(hh, mkv2(w1.x, w1.y), la[2]);
                    la[3] = pkfma(hh, mkv2(w1.z, w1.w), la[3]);
                }
            }
            float4 o0, o1;
            o0.x = la[0].x; o0.y = la[0].y; o0.z = la[1].x; o0.w = la[1].y;
            o1.x = la[2].x; o1.y = la[2].y; o1.z = la[3].x; o1.w = la[3].y;
            *(float4*)(hq + 8 * sq) = o0;
            *(float4*)(hq + 8 * sq + 4) = o1;
        }

        // ---- read 25 logits for my prob (dup x4)
        float l25[25];
        {
            const float4 r0 = *(const float4*)(hq + 0);
            const float4 r1 = *(const float4*)(hq + 4);
            const float4 r2 = *(const float4*)(hq + 8);
            const float4 r3 = *(const float4*)(hq + 12);
            const float4 r4 = *(const float4*)(hq + 16);
            const float4 r5 = *(const float4*)(hq + 20);
            l25[0] = r0.x; l25[1] = r0.y; l25[2] = r0.z; l25[3] = r0.w;
            l25[4] = r1.x; l25[5] = r1.y; l25[6] = r1.z; l25[7] = r1.w;
            l25[8] = r2.x; l25[9] = r2.y; l25[10] = r2.z; l25[11] = r2.w;
            l25[12] = r3.x; l25[13] = r3.y; l25[14] = r3.z; l25[15] = r3.w;
            l25[16] = r4.x; l25[17] = r4.y; l25[18] = r4.z; l25[19] = r4.w;
            l25[20] = r5.x; l25[21] = r5.y; l25[22] = r5.z; l25[23] = r5.w;
            l25[24] = hq[24];
        }

        // softmax(5 * logits) over 25
        float zm = -3.4028235e38f;
#pragma unroll
        for (int j = 0; j < 25; ++j) {
            l25[j] = 5.0f * l25[j];
            zm = fmaxf(zm, l25[j]);
        }
        float ssum = 0.f;
#pragma unroll
        for (int j = 0; j < 25; ++j) {
            l25[j] = expf(l25[j] - zm);
            ssum += l25[j];
        }
        const float inv = 1.0f / ssum;

        float tf[12];
#pragma unroll
        for (int r = 0; r < 12; ++r) tf[r] = 0.f;
#pragma unroll
        for (int j = 0; j < 24; ++j) {
            const float wj = l25[j] * inv;
            const float* T = transforms + j * 16;
#pragma unroll
            for (int r = 0; r < 12; ++r) tf[r] = fmaf(wj, T[r], tf[r]);
        }
        {
            const float wj = l25[24] * inv;  // identity transform
            tf[0] += wj; tf[5] += wj; tf[10] += wj;
        }
        const float r0 = fmaf(tf[0], cx0, fmaf(tf[1], cx1, fmaf(tf[2], cx2, tf[3])));
        const float r1 = fmaf(tf[4], cx0, fmaf(tf[5], cx1, fmaf(tf[6], cx2, tf[7])));
        const float r2 = fmaf(tf[8], cx0, fmaf(tf[9], cx1, fmaf(tf[10], cx2, tf[11])));

        if (step == 8) {
            if (sq == 0 && m < M) {
                const float nopt = STS(21);
                out[(size_t)m * 3 + 0] = r0;
                out[(size_t)m * 3 + 1] = r1;
                out[(size_t)m * 3 + 2] = r2;
                float* xopt_out = out + (size_t)M * 3;
                xopt_out[(size_t)m * 3 + 0] = cx0;
                xopt_out[(size_t)m * 3 + 1] = cx1;
                xopt_out[(size_t)m * 3 + 2] = cx2;
                out[(size_t)M * 6 + m] = nopt;
                out[(size_t)M * 7 + m] = (nopt < 1e-5f) ? 1.0f : 0.0f;
            }
            break;
        }

        const float g0 = r0 - tx, g1 = r1 - ty, g2 = r2 - tz;

        if (step == -1) {
            gx0 = g0; gx1 = g1; gx2 = g2;
            const float gn = sqrtf(g0 * g0 + g1 * g1 + g2 * g2);
            STS(21) = gn;                                  // nopt
            STS(9) = -g0; STS(10) = -g1; STS(11) = -g2;    // up (Jinv = I)
            STS(18) = xk0; STS(19) = xk1; STS(20) = xk2;   // xo
            STS(12) = 0.f; STS(13) = 0.f; STS(14) = 0.f;   // dx
            STS(15) = 0.f; STS(16) = 0.f; STS(17) = 0.f;   // dg
            STS(0) = 1.f; STS(1) = 0.f; STS(2) = 0.f;
            STS(3) = 0.f; STS(4) = 1.f; STS(5) = 0.f;
            STS(6) = 0.f; STS(7) = 0.f; STS(8) = 1.f;
        } else {
            float J00 = STS(0), J01 = STS(1), J02 = STS(2);
            float J10 = STS(3), J11 = STS(4), J12 = STS(5);
            float J20 = STS(6), J21 = STS(7), J22 = STS(8);
            const float dx0 = STS(12), dx1 = STS(13), dx2 = STS(14);
            float dg0 = STS(15), dg1 = STS(16), dg2 = STS(17);
            float nopt = STS(21);
            if (m3) {
                dg0 = g0 - gx0; dg1 = g1 - gx1; dg2 = g2 - gx2;
                gx0 += dg0; gx1 += dg1; gx2 += dg2;
                STS(15) = dg0; STS(16) = dg1; STS(17) = dg2;
            }
            const float gn = sqrtf(gx0 * gx0 + gx1 * gx1 + gx2 * gx2);
            const bool better = gn < nopt;
            if (better) {
                nopt = gn;
                STS(21) = gn;
                STS(18) = xk0; STS(19) = xk1; STS(20) = xk2;
            }
            mask = (nopt > 1e-5f) && (gn < 1.0f) && (m < M);

            const float v0 = dx0 * J00 + dx1 * J10 + dx2 * J20;
            const float v1 = dx0 * J01 + dx1 * J11 + dx2 * J21;
            const float v2 = dx0 * J02 + dx1 * J12 + dx2 * J22;
            const float Jd0 = J00 * dg0 + J01 * dg1 + J02 * dg2;
            const float Jd1 = J10 * dg0 + J11 * dg1 + J12 * dg2;
            const float Jd2 = J20 * dg0 + J21 * dg1 + J22 * dg2;
            const float a0 = dx0 - Jd0, a1 = dx1 - Jd1, a2 = dx2 - Jd2;
            float bden = v0 * dg0 + v1 * dg1 + v2 * dg2;
            bden += (bden >= 0.f) ? 1e-6f : -1e-6f;
            if (mask) {
                const float q0 = a0 / bden, q1 = a1 / bden, q2 = a2 / bden;
                J00 = fmaf(q0, v0, J00); J01 = fmaf(q0, v1, J01); J02 = fmaf(q0, v2, J02);
                J10 = fmaf(q1, v0, J10); J11 = fmaf(q1, v1, J11); J12 = fmaf(q1, v2, J12);
                J20 = fmaf(q2, v0, J20); J21 = fmaf(q2, v1, J21); J22 = fmaf(q2, v2, J22);
                STS(0) = J00; STS(1) = J01; STS(2) = J02;
                STS(3) = J10; STS(4) = J11; STS(5) = J12;
                STS(6) = J20; STS(7) = J21; STS(8) = J22;
            }
            if (m3) {
                STS(9) = -(J00 * gx0 + J01 * gx1 + J02 * gx2);
                STS(10) = -(J10 * gx0 + J11 * gx1 + J12 * gx2);
                STS(11) = -(J20 * gx0 + J21 * gx1 + J22 * gx2);
            }
        }
        ++step;
    }
#undef STS
}

extern "C" void kernel_launch(void* const* d_in, const int* in_sizes, int n_in,
                              void* d_out, int out_size, void* d_ws, size_t ws_size,
                              hipStream_t stream) {
    const float* x = (const float*)d_in[0];
    const float* bone_pts = (const float*)d_in[1];
    const float* transforms = (const float*)d_in[2];
    const float* delta_tf = (const float*)d_in[3];
    const float* W0 = (const float*)d_in[4];
    const float* b0 = (const float*)d_in[5];
    const float* W1 = (const float*)d_in[6];
    const float* b1 = (const float*)d_in[7];
    const float* W2 = (const float*)d_in[8];
    const float* b2 = (const float*)d_in[9];
    const float* W3 = (const float*)d_in[10];
    const float* b3 = (const float*)d_in[11];
    const float* W4 = (const float*)d_in[12];
    const float* b4 = (const float*)d_in[13];
    float* out = (float*)d_out;

    float* W0p = (float*)d_ws;    // 32*128
    float* W4p = W0p + 32 * 128;  // 128*32
    float* b4p = W4p + 128 * 32;  // 32

    prep_kernel<<<16, 256, 0, stream>>>(W0, W4, b4, W0p, W4p, b4p);

    const int Npts = in_sizes[0] / 3;
    const int M = Npts * 6;
    const int blocks = (M + PPB - 1) / PPB;
    snarf_kernel<<<blocks, BLOCK, 0, stream>>>(
        x, bone_pts, transforms, delta_tf, W0p, b0, W1, b1, W2, b2, W3, b3,
        W4p, b4p, out, Npts);
}

// Round 10
// 2398.468 us; speedup vs baseline: 7.9048x; 7.9048x over previous
//
#include <hip/hip_runtime.h>
#include <math.h>

#define BLOCK 256
#define PPB 64     // problems per block (16 per wave)
#define HP 132     // floats per problem h-column (128 + 4 pad; 4·33 -> float4-aligned)

typedef float v2f __attribute__((ext_vector_type(2)));

__device__ __forceinline__ v2f mkv2(float a, float b) {
    v2f r; r.x = a; r.y = b; return r;
}
__device__ __forceinline__ v2f pkfma(v2f a, v2f b, v2f c) {
#if __has_builtin(__builtin_elementwise_fma)
    return __builtin_elementwise_fma(a, b, c);
#else
    return mkv2(fmaf(a.x, b.x, c.x), fmaf(a.y, b.y, c.y));
#endif
}
__device__ __forceinline__ float f4el(const float4& v, int r) {
    return (r == 0) ? v.x : (r == 1) ? v.y : (r == 2) ? v.z : v.w;
}

// prep: W0 [27][128] -> W0p [32][128] (zero rows); W4 [128][25] -> W4p [128][32]
// (zero cols); b4 [25] -> b4p [32]
__global__ void prep_kernel(const float* __restrict__ W0, const float* __restrict__ W4,
                            const float* __restrict__ b4, float* __restrict__ W0p,
                            float* __restrict__ W4p, float* __restrict__ b4p) {
    const int t = blockIdx.x * blockDim.x + threadIdx.x;
    if (t < 32 * 128) {
        const int k = t >> 7, j = t & 127;
        W0p[t] = (k < 27) ? W0[k * 128 + j] : 0.0f;
    }
    if (t < 128 * 32) {
        const int k = t >> 5, j = t & 31;
        W4p[t] = (j < 25) ? W4[k * 25 + j] : 0.0f;
    }
    if (t < 32) b4p[t] = (t < 25) ? b4[t] : 0.0f;
}

// main layer: lane owns 8 cols x 4 probs. Wc = W + 8*cg (row stride WS),
// bc = b + 8*cg, hg = h base of prob group (4*gg), hwr = hg + 8*cg.
// Batch of 4 k-rows: 8 weight float4 + 4 h float4 loads issued together,
// then 64 pkfma. unroll 2 lets the compiler overlap next-batch loads with
// current-batch FMAs inside the 128-VGPR cap (no explicit double-buffer!).
// NOTE: h pointers intentionally NOT __restrict__ (same buffer; lockstep wave
// ordering makes read-then-write safe).
template <int K, int WS>
__device__ __forceinline__ void layerM(const float* __restrict__ Wc,
                                       const float* __restrict__ bc,
                                       const float* hg, float* hwr) {
    constexpr int NB = K / 4;
    v2f acc[16];
    {
        const float4 b0 = *(const float4*)(bc);
        const float4 b1 = *(const float4*)(bc + 4);
#pragma unroll
        for (int p = 0; p < 4; ++p) {
            acc[p * 4 + 0] = mkv2(b0.x, b0.y);
            acc[p * 4 + 1] = mkv2(b0.z, b0.w);
            acc[p * 4 + 2] = mkv2(b1.x, b1.y);
            acc[p * 4 + 3] = mkv2(b1.z, b1.w);
        }
    }
#pragma unroll 2
    for (int kb = 0; kb < NB; ++kb) {
        float4 h4[4];
#pragma unroll
        for (int p = 0; p < 4; ++p)
            h4[p] = *(const float4*)(hg + p * HP + kb * 4);
        float4 w0[4], w1[4];
#pragma unroll
        for (int r = 0; r < 4; ++r) {
            w0[r] = *(const float4*)(Wc + (kb * 4 + r) * WS);
            w1[r] = *(const float4*)(Wc + (kb * 4 + r) * WS + 4);
        }
#pragma unroll
        for (int r = 0; r < 4; ++r) {
            const v2f wa = mkv2(w0[r].x, w0[r].y);
            const v2f wb = mkv2(w0[r].z, w0[r].w);
            const v2f wc = mkv2(w1[r].x, w1[r].y);
            const v2f wd = mkv2(w1[r].z, w1[r].w);
#pragma unroll
            for (int p = 0; p < 4; ++p) {
                const float hv = f4el(h4[p], r);
                const v2f hh = mkv2(hv, hv);
                acc[p * 4 + 0] = pkfma(hh, wa, acc[p * 4 + 0]);
                acc[p * 4 + 1] = pkfma(hh, wb, acc[p * 4 + 1]);
                acc[p * 4 + 2] = pkfma(hh, wc, acc[p * 4 + 2]);
                acc[p * 4 + 3] = pkfma(hh, wd, acc[p * 4 + 3]);
            }
        }
    }
#pragma unroll
    for (int p = 0; p < 4; ++p) {
        float4 o0, o1;
        o0.x = fmaxf(acc[p * 4 + 0].x, 0.f); o0.y = fmaxf(acc[p * 4 + 0].y, 0.f);
        o0.z = fmaxf(acc[p * 4 + 1].x, 0.f); o0.w = fmaxf(acc[p * 4 + 1].y, 0.f);
        o1.x = fmaxf(acc[p * 4 + 2].x, 0.f); o1.y = fmaxf(acc[p * 4 + 2].y, 0.f);
        o1.z = fmaxf(acc[p * 4 + 3].x, 0.f); o1.w = fmaxf(acc[p * 4 + 3].y, 0.f);
        *(float4*)(hwr + p * HP) = o0;
        *(float4*)(hwr + p * HP + 4) = o1;
    }
}

__global__ __launch_bounds__(BLOCK)
__attribute__((amdgpu_num_vgpr(128))) void snarf_kernel(
    const float* __restrict__ xin, const float* __restrict__ bone_pts,
    const float* __restrict__ transforms, const float* __restrict__ delta_tf,
    const float* __restrict__ W0p, const float* __restrict__ b0,
    const float* __restrict__ W1, const float* __restrict__ b1,
    const float* __restrict__ W2, const float* __restrict__ b2,
    const float* __restrict__ W3, const float* __restrict__ b3,
    const float* __restrict__ W4p, const float* __restrict__ b4p,
    float* __restrict__ out, int Npts) {
    __shared__ float hL[PPB * HP];      // 33792 B, h[prob][k]
    __shared__ float stL[22 * PPB];     // 5632 B solver state  (total 39424 B)
    const int tid = threadIdx.x;
    const int wid = tid >> 6;
    const int lane = tid & 63;
    const int p16 = lane & 15;   // my prob (epilogue/pe/last-layer mapping)
    const int sq = lane >> 4;    // duplicate group 0..3
    const int cg = lane >> 2;    // main-layer col group 0..15 (8 cols)
    const int gg = lane & 3;     // main-layer prob group 0..3 (4 probs)
    const int M = Npts * 6;
    const int m = blockIdx.x * PPB + wid * 16 + p16;
    const int mc = (m < M) ? m : (M - 1);
    const int n = mc / 6;
    const int i = mc - n * 6;

    float* hWv = &hL[wid * 16 * HP];          // wave's 16 prob columns
    const float* hg = hWv + (4 * gg) * HP;    // k-loop read base (4 probs)
    float* hwr = hWv + (4 * gg) * HP + 8 * cg;
    float* hq = hWv + p16 * HP;               // my prob's column
    volatile float* st = &stL[wid * 16 + p16];
#define STS(idx) st[(idx) * PPB]

    const float tx = xin[n * 3 + 0], ty = xin[n * 3 + 1], tz = xin[n * 3 + 2];

    // ---- init candidate (duplicated across sq; bitwise identical)
    float xk0, xk1, xk2;
    if (i < 5) {
        float dprev = -1.0f;
        int jprev = -1;
        for (int r = 0; r <= i; ++r) {
            float bd = 3.4028235e38f;
            int bj = 0;
            for (int j = 0; j < 24; ++j) {
                const float ax = tx - bone_pts[j * 3 + 0];
                const float ay = ty - bone_pts[j * 3 + 1];
                const float az = tz - bone_pts[j * 3 + 2];
                const float d = sqrtf(ax * ax + ay * ay + az * az);
                const bool taken = (d < dprev) || (d == dprev && j <= jprev);
                if (!taken && d < bd) { bd = d; bj = j; }
            }
            dprev = bd;
            jprev = bj;
        }
        const float* T = delta_tf + jprev * 16;
        xk0 = fmaf(T[0], tx, fmaf(T[1], ty, fmaf(T[2], tz, T[3])));
        xk1 = fmaf(T[4], tx, fmaf(T[5], ty, fmaf(T[6], tz, T[7])));
        xk2 = fmaf(T[8], tx, fmaf(T[9], ty, fmaf(T[10], tz, T[11])));
    } else {
        xk0 = tx; xk1 = ty; xk2 = tz;
    }

    float gx0 = 0.f, gx1 = 0.f, gx2 = 0.f;
    bool mask = (m < M);

    int step = -1;  // -1 init eval, 0..7 Broyden, 8 final eval
    while (step <= 8) {
        bool m3 = mask;
        if (step >= 0 && step < 8) {
            if (__ballot(mask) == 0ull) { step = 8; continue; }  // wave-local exit
            if (m3) {
                const float u0 = STS(9), u1 = STS(10), u2 = STS(11);
                STS(12) = u0; STS(13) = u1; STS(14) = u2;  // dx = up
                xk0 += u0; xk1 += u1; xk2 += u2;
            }
        }
        float cx0 = xk0, cx1 = xk1, cx2 = xk2;
        if (step == 8) { cx0 = STS(18); cx1 = STS(19); cx2 = STS(20); }

        // ---- positional encoding: all 12 sincos (dup x4); sq writes its 8 rows
        float s1x, c1x, s1y, c1y, s1z, c1z;
        float s2x, c2x, s2y, c2y, s2z, c2z;
        float s4x, c4x, s4y, c4y, s4z, c4z;
        float s8x, c8x, s8y, c8y, s8z, c8z;
        sincosf(cx0, &s1x, &c1x); sincosf(cx1, &s1y, &c1y); sincosf(cx2, &s1z, &c1z);
        sincosf(2.f * cx0, &s2x, &c2x); sincosf(2.f * cx1, &s2y, &c2y); sincosf(2.f * cx2, &s2z, &c2z);
        sincosf(4.f * cx0, &s4x, &c4x); sincosf(4.f * cx1, &s4y, &c4y); sincosf(4.f * cx2, &s4z, &c4z);
        sincosf(8.f * cx0, &s8x, &c8x); sincosf(8.f * cx1, &s8y, &c8y); sincosf(8.f * cx2, &s8z, &c8z);
        {
            float4 a, b;
            if (sq == 0) {
                a.x = cx0; a.y = cx1; a.z = cx2; a.w = s1x;
                b.x = s1y; b.y = s1z; b.z = s2x; b.w = s2y;
            } else if (sq == 1) {
                a.x = s2z; a.y = s4x; a.z = s4y; a.w = s4z;
                b.x = s8x; b.y = s8y; b.z = s8z; b.w = c1x;
            } else if (sq == 2) {
                a.x = c1y; a.y = c1z; a.z = c2x; a.w = c2y;
                b.x = c2z; b.y = c4x; b.z = c4y; b.w = c4z;
            } else {
                a.x = c8x; a.y = c8y; a.z = c8z; a.w = 0.f;
                b.x = 0.f; b.y = 0.f; b.z = 0.f; b.w = 0.f;
            }
            *(float4*)(hq + sq * 8) = a;
            *(float4*)(hq + sq * 8 + 4) = b;
        }

        layerM<32, 128>(W0p + 8 * cg, b0 + 8 * cg, hg, hwr);
        layerM<128, 128>(W1 + 8 * cg, b1 + 8 * cg, hg, hwr);
        layerM<128, 128>(W2 + 8 * cg, b2 + 8 * cg, hg, hwr);
        layerM<128, 128>(W3 + 8 * cg, b3 + 8 * cg, hg, hwr);

        // ---- output layer: lane (sq, p16) computes cols 8sq..8sq+8 of prob p16
        {
            v2f la[4];
            const float* bc = b4p + 8 * sq;
            const float4 bb0 = *(const float4*)(bc);
            const float4 bb1 = *(const float4*)(bc + 4);
            la[0] = mkv2(bb0.x, bb0.y); la[1] = mkv2(bb0.z, bb0.w);
            la[2] = mkv2(bb1.x, bb1.y); la[3] = mkv2(bb1.z, bb1.w);
            const float* Wc = W4p + 8 * sq;
#pragma unroll 2
            for (int kb = 0; kb < 32; ++kb) {
                const float4 h4 = *(const float4*)(hq + kb * 4);
#pragma unroll
                for (int r = 0; r < 4; ++r) {
                    const int k = kb * 4 + r;
                    const float4 w0 = *(const float4*)(Wc + k * 32);
                    const float4 w1 = *(const float4*)(Wc + k * 32 + 4);
                    const float hv = f4el(h4, r);
                    const v2f hh = mkv2(hv, hv);
                    la[0] = pkfma(hh, mkv2(w0.x, w0.y), la[0]);
                    la[1] = pkfma(hh, mkv2(w0.z, w0.w), la[1]);
                    la[2] = pkfma(hh, mkv2(w1.x, w1.y), la[2]);
                    la[3] = pkfma(hh, mkv2(w1.z, w1.w), la[3]);
                }
            }
            float4 o0, o1;
            o0.x = la[0].x; o0.y = la[0].y; o0.z = la[1].x; o0.w = la[1].y;
            o1.x = la[2].x; o1.y = la[2].y; o1.z = la[3].x; o1.w = la[3].y;
            *(float4*)(hq + 8 * sq) = o0;
            *(float4*)(hq + 8 * sq + 4) = o1;
        }

        // ---- read 25 logits for my prob (dup x4)
        float l25[25];
        {
            const float4 r0 = *(const float4*)(hq + 0);
            const float4 r1 = *(const float4*)(hq + 4);
            const float4 r2 = *(const float4*)(hq + 8);
            const float4 r3 = *(const float4*)(hq + 12);
            const float4 r4 = *(const float4*)(hq + 16);
            const float4 r5 = *(const float4*)(hq + 20);
            l25[0] = r0.x; l25[1] = r0.y; l25[2] = r0.z; l25[3] = r0.w;
            l25[4] = r1.x; l25[5] = r1.y; l25[6] = r1.z; l25[7] = r1.w;
            l25[8] = r2.x; l25[9] = r2.y; l25[10] = r2.z; l25[11] = r2.w;
            l25[12] = r3.x; l25[13] = r3.y; l25[14] = r3.z; l25[15] = r3.w;
            l25[16] = r4.x; l25[17] = r4.y; l25[18] = r4.z; l25[19] = r4.w;
            l25[20] = r5.x; l25[21] = r5.y; l25[22] = r5.z; l25[23] = r5.w;
            l25[24] = hq[24];
        }

        // softmax(5 * logits) over 25
        float zm = -3.4028235e38f;
#pragma unroll
        for (int j = 0; j < 25; ++j) {
            l25[j] = 5.0f * l25[j];
            zm = fmaxf(zm, l25[j]);
        }
        float ssum = 0.f;
#pragma unroll
        for (int j = 0; j < 25; ++j) {
            l25[j] = expf(l25[j] - zm);
            ssum += l25[j];
        }
        const float inv = 1.0f / ssum;

        float tf[12];
#pragma unroll
        for (int r = 0; r < 12; ++r) tf[r] = 0.f;
#pragma unroll
        for (int j = 0; j < 24; ++j) {
            const float wj = l25[j] * inv;
            const float* T = transforms + j * 16;
#pragma unroll
            for (int r = 0; r < 12; ++r) tf[r] = fmaf(wj, T[r], tf[r]);
        }
        {
            const float wj = l25[24] * inv;  // identity transform
            tf[0] += wj; tf[5] += wj; tf[10] += wj;
        }
        const float r0 = fmaf(tf[0], cx0, fmaf(tf[1], cx1, fmaf(tf[2], cx2, tf[3])));
        const float r1 = fmaf(tf[4], cx0, fmaf(tf[5], cx1, fmaf(tf[6], cx2, tf[7])));
        const float r2 = fmaf(tf[8], cx0, fmaf(tf[9], cx1, fmaf(tf[10], cx2, tf[11])));

        if (step == 8) {
            if (sq == 0 && m < M) {
                const float nopt = STS(21);
                out[(size_t)m * 3 + 0] = r0;
                out[(size_t)m * 3 + 1] = r1;
                out[(size_t)m * 3 + 2] = r2;
                float* xopt_out = out + (size_t)M * 3;
                xopt_out[(size_t)m * 3 + 0] = cx0;
                xopt_out[(size_t)m * 3 + 1] = cx1;
                xopt_out[(size_t)m * 3 + 2] = cx2;
                out[(size_t)M * 6 + m] = nopt;
                out[(size_t)M * 7 + m] = (nopt < 1e-5f) ? 1.0f : 0.0f;
            }
            break;
        }

        const float g0 = r0 - tx, g1 = r1 - ty, g2 = r2 - tz;

        if (step == -1) {
            gx0 = g0; gx1 = g1; gx2 = g2;
            const float gn = sqrtf(g0 * g0 + g1 * g1 + g2 * g2);
            STS(21) = gn;                                  // nopt
            STS(9) = -g0; STS(10) = -g1; STS(11) = -g2;    // up (Jinv = I)
            STS(18) = xk0; STS(19) = xk1; STS(20) = xk2;   // xo
            STS(12) = 0.f; STS(13) = 0.f; STS(14) = 0.f;   // dx
            STS(15) = 0.f; STS(16) = 0.f; STS(17) = 0.f;   // dg
            STS(0) = 1.f; STS(1) = 0.f; STS(2) = 0.f;
            STS(3) = 0.f; STS(4) = 1.f; STS(5) = 0.f;
            STS(6) = 0.f; STS(7) = 0.f; STS(8) = 1.f;
        } else {
            float J00 = STS(0), J01 = STS(1), J02 = STS(2);
            float J10 = STS(3), J11 = STS(4), J12 = STS(5);
            float J20 = STS(6), J21 = STS(7), J22 = STS(8);
            const float dx0 = STS(12), dx1 = STS(13), dx2 = STS(14);
            float dg0 = STS(15), dg1 = STS(16), dg2 = STS(17);
            float nopt = STS(21);
            if (m3) {
                dg0 = g0 - gx0; dg1 = g1 - gx1; dg2 = g2 - gx2;
                gx0 += dg0; gx1 += dg1; gx2 += dg2;
                STS(15) = dg0; STS(16) = dg1; STS(17) = dg2;
            }
            const float gn = sqrtf(gx0 * gx0 + gx1 * gx1 + gx2 * gx2);
            const bool better = gn < nopt;
            if (better) {
                nopt = gn;
                STS(21) = gn;
                STS(18) = xk0; STS(19) = xk1; STS(20) = xk2;
            }
            mask = (nopt > 1e-5f) && (gn < 1.0f) && (m < M);

            const float v0 = dx0 * J00 + dx1 * J10 + dx2 * J20;
            const float v1 = dx0 * J01 + dx1 * J11 + dx2 * J21;
            const float v2 = dx0 * J02 + dx1 * J12 + dx2 * J22;
            const float Jd0 = J00 * dg0 + J01 * dg1 + J02 * dg2;
            const float Jd1 = J10 * dg0 + J11 * dg1 + J12 * dg2;
            const float Jd2 = J20 * dg0 + J21 * dg1 + J22 * dg2;
            const float a0 = dx0 - Jd0, a1 = dx1 - Jd1, a2 = dx2 - Jd2;
            float bden = v0 * dg0 + v1 * dg1 + v2 * dg2;
            bden += (bden >= 0.f) ? 1e-6f : -1e-6f;
            if (mask) {
                const float q0 = a0 / bden, q1 = a1 / bden, q2 = a2 / bden;
                J00 = fmaf(q0, v0, J00); J01 = fmaf(q0, v1, J01); J02 = fmaf(q0, v2, J02);
                J10 = fmaf(q1, v0, J10); J11 = fmaf(q1, v1, J11); J12 = fmaf(q1, v2, J12);
                J20 = fmaf(q2, v0, J20); J21 = fmaf(q2, v1, J21); J22 = fmaf(q2, v2, J22);
                STS(0) = J00; STS(1) = J01; STS(2) = J02;
                STS(3) = J10; STS(4) = J11; STS(5) = J12;
                STS(6) = J20; STS(7) = J21; STS(8) = J22;
            }
            if (m3) {
                STS(9) = -(J00 * gx0 + J01 * gx1 + J02 * gx2);
                STS(10) = -(J10 * gx0 + J11 * gx1 + J12 * gx2);
                STS(11) = -(J20 * gx0 + J21 * gx1 + J22 * gx2);
            }
        }
        ++step;
    }
#undef STS
}

extern "C" void kernel_launch(void* const* d_in, const int* in_sizes, int n_in,
                              void* d_out, int out_size, void* d_ws, size_t ws_size,
                              hipStream_t stream) {
    const float* x = (const float*)d_in[0];
    const float* bone_pts = (const float*)d_in[1];
    const float* transforms = (const float*)d_in[2];
    const float* delta_tf = (const float*)d_in[3];
    const float* W0 = (const float*)d_in[4];
    const float* b0 = (const float*)d_in[5];
    const float* W1 = (const float*)d_in[6];
    const float* b1 = (const float*)d_in[7];
    const float* W2 = (const float*)d_in[8];
    const float* b2 = (const float*)d_in[9];
    const float* W3 = (const float*)d_in[10];
    const float* b3 = (const float*)d_in[11];
    const float* W4 = (const float*)d_in[12];
    const float* b4 = (const float*)d_in[13];
    float* out = (float*)d_out;

    float* W0p = (float*)d_ws;    // 32*128
    float* W4p = W0p + 32 * 128;  // 128*32
    float* b4p = W4p + 128 * 32;  // 32

    prep_kernel<<<16, 256, 0, stream>>>(W0, W4, b4, W0p, W4p, b4p);

    const int Npts = in_sizes[0] / 3;
    const int M = Npts * 6;
    const int blocks = (M + PPB - 1) / PPB;
    snarf_kernel<<<blocks, BLOCK, 0, stream>>>(
        x, bone_pts, transforms, delta_tf, W0p, b0, W1, b1, W2, b2, W3, b3,
        W4p, b4p, out, Npts);
}

// Round 11
// 2027.103 us; speedup vs baseline: 9.3530x; 1.1832x over previous
//
#include <hip/hip_runtime.h>
#include <math.h>

#define BLOCK 256
#define PPB 64     // problems per block (16 per wave)
#define HP 132     // h row stride per prob (128 + 4 pad)
#define WCOLS 2136 // per-wave h region floats: 16*132 + 3*8 swizzle pad

typedef float v2f __attribute__((ext_vector_type(2)));

__device__ __forceinline__ v2f mkv2(float a, float b) {
    v2f r; r.x = a; r.y = b; return r;
}
__device__ __forceinline__ v2f pkfma(v2f a, v2f b, v2f c) {
#if __has_builtin(__builtin_elementwise_fma)
    return __builtin_elementwise_fma(a, b, c);
#else
    return mkv2(fmaf(a.x, b.x, c.x), fmaf(a.y, b.y, c.y));
#endif
}
__device__ __forceinline__ float f4el(const float4& v, int r) {
    return (r == 0) ? v.x : (r == 1) ? v.y : (r == 2) ? v.z : v.w;
}
// swizzled column base: prob p -> p*132 + (p>>2)*8  (gg stride 536 ≡ 24 mod 32
// banks -> the 4 gg addresses of one ds_read land on bank quads {0,24,16,8})
__device__ __forceinline__ int col_base(int p) { return p * HP + ((p >> 2) << 3); }

// prep: W0 [27][128] -> W0p [32][128] (zero rows); W4 [128][25] -> W4p [128][32]
// (zero cols); b4 [25] -> b4p [32]
__global__ void prep_kernel(const float* __restrict__ W0, const float* __restrict__ W4,
                            const float* __restrict__ b4, float* __restrict__ W0p,
                            float* __restrict__ W4p, float* __restrict__ b4p) {
    const int t = blockIdx.x * blockDim.x + threadIdx.x;
    if (t < 32 * 128) {
        const int k = t >> 7, j = t & 127;
        W0p[t] = (k < 27) ? W0[k * 128 + j] : 0.0f;
    }
    if (t < 128 * 32) {
        const int k = t >> 5, j = t & 31;
        W4p[t] = (j < 25) ? W4[k * 25 + j] : 0.0f;
    }
    if (t < 32) b4p[t] = (t < 25) ? b4[t] : 0.0f;
}

// main layer: lane owns 8 cols x 4 probs (its gg group). Batch of 4 k-rows:
// 8 weight float4 + 4 h float4 loads issued together, then 64 pkfma; unroll 2
// lets the compiler overlap next-batch loads under current FMAs within 128 VGPR.
template <int K, int WS>
__device__ __forceinline__ void layerM(const float* __restrict__ Wc,
                                       const float* __restrict__ bc,
                                       const float* hg, float* hwr) {
    constexpr int NB = K / 4;
    v2f acc[16];
    {
        const float4 b0 = *(const float4*)(bc);
        const float4 b1 = *(const float4*)(bc + 4);
#pragma unroll
        for (int p = 0; p < 4; ++p) {
            acc[p * 4 + 0] = mkv2(b0.x, b0.y);
            acc[p * 4 + 1] = mkv2(b0.z, b0.w);
            acc[p * 4 + 2] = mkv2(b1.x, b1.y);
            acc[p * 4 + 3] = mkv2(b1.z, b1.w);
        }
    }
#pragma unroll 2
    for (int kb = 0; kb < NB; ++kb) {
        float4 h4[4];
#pragma unroll
        for (int p = 0; p < 4; ++p)
            h4[p] = *(const float4*)(hg + p * HP + kb * 4);
        float4 w0[4], w1[4];
#pragma unroll
        for (int r = 0; r < 4; ++r) {
            w0[r] = *(const float4*)(Wc + (kb * 4 + r) * WS);
            w1[r] = *(const float4*)(Wc + (kb * 4 + r) * WS + 4);
        }
#pragma unroll
        for (int r = 0; r < 4; ++r) {
            const v2f wa = mkv2(w0[r].x, w0[r].y);
            const v2f wb = mkv2(w0[r].z, w0[r].w);
            const v2f wc = mkv2(w1[r].x, w1[r].y);
            const v2f wd = mkv2(w1[r].z, w1[r].w);
#pragma unroll
            for (int p = 0; p < 4; ++p) {
                const float hv = f4el(h4[p], r);
                const v2f hh = mkv2(hv, hv);
                acc[p * 4 + 0] = pkfma(hh, wa, acc[p * 4 + 0]);
                acc[p * 4 + 1] = pkfma(hh, wb, acc[p * 4 + 1]);
                acc[p * 4 + 2] = pkfma(hh, wc, acc[p * 4 + 2]);
                acc[p * 4 + 3] = pkfma(hh, wd, acc[p * 4 + 3]);
            }
        }
    }
#pragma unroll
    for (int p = 0; p < 4; ++p) {
        float4 o0, o1;
        o0.x = fmaxf(acc[p * 4 + 0].x, 0.f); o0.y = fmaxf(acc[p * 4 + 0].y, 0.f);
        o0.z = fmaxf(acc[p * 4 + 1].x, 0.f); o0.w = fmaxf(acc[p * 4 + 1].y, 0.f);
        o1.x = fmaxf(acc[p * 4 + 2].x, 0.f); o1.y = fmaxf(acc[p * 4 + 2].y, 0.f);
        o1.z = fmaxf(acc[p * 4 + 3].x, 0.f); o1.w = fmaxf(acc[p * 4 + 3].y, 0.f);
        *(float4*)(hwr + p * HP) = o0;
        *(float4*)(hwr + p * HP + 4) = o1;
    }
}

// LDS solver state slots: 0..8 J, 9..11 up, 12..14 dx, 15..17 dg, 18..20 xo,
// 21 nopt, 22..24 rw (= tf(xopt)·xopt + off, cached -> no final eval needed)
__global__ __launch_bounds__(BLOCK)
__attribute__((amdgpu_num_vgpr(128))) void snarf_kernel(
    const float* __restrict__ xin, const float* __restrict__ bone_pts,
    const float* __restrict__ transforms, const float* __restrict__ delta_tf,
    const float* __restrict__ W0p, const float* __restrict__ b0,
    const float* __restrict__ W1, const float* __restrict__ b1,
    const float* __restrict__ W2, const float* __restrict__ b2,
    const float* __restrict__ W3, const float* __restrict__ b3,
    const float* __restrict__ W4p, const float* __restrict__ b4p,
    float* __restrict__ out, int Npts) {
    __shared__ float hL[4 * WCOLS];     // 34176 B, swizzled h[prob][k]
    __shared__ float stL[25 * PPB];     // 6400 B solver state (total 40576 B)
    const int tid = threadIdx.x;
    const int wid = tid >> 6;
    const int lane = tid & 63;
    const int p16 = lane & 15;   // my prob (pe/output-layer/epilogue mapping)
    const int sq = lane >> 4;    // duplicate group 0..3 (owns pe scale 1<<sq)
    const int cg = lane >> 2;    // main-layer col group 0..15 (8 cols)
    const int gg = lane & 3;     // main-layer prob group 0..3 (4 probs)
    const int M = Npts * 6;
    const int m = blockIdx.x * PPB + wid * 16 + p16;
    const int mc = (m < M) ? m : (M - 1);
    const int n = mc / 6;
    const int i = mc - n * 6;

    float* hWv = &hL[wid * WCOLS];            // wave's 16 swizzled prob columns
    const float* hg = hWv + gg * 536;         // k-loop read base (col_base(4gg))
    float* hwr = hWv + gg * 536 + 8 * cg;     // my writeback base
    float* hq = hWv + col_base(p16);          // my prob's column
    volatile float* st = &stL[wid * 16 + p16];
#define STS(idx) st[(idx) * PPB]

    const float tx = xin[n * 3 + 0], ty = xin[n * 3 + 1], tz = xin[n * 3 + 2];

    // ---- init candidate (duplicated across sq; bitwise identical)
    float xk0, xk1, xk2;
    if (i < 5) {
        float dprev = -1.0f;
        int jprev = -1;
        for (int r = 0; r <= i; ++r) {
            float bd = 3.4028235e38f;
            int bj = 0;
            for (int j = 0; j < 24; ++j) {
                const float ax = tx - bone_pts[j * 3 + 0];
                const float ay = ty - bone_pts[j * 3 + 1];
                const float az = tz - bone_pts[j * 3 + 2];
                const float d = sqrtf(ax * ax + ay * ay + az * az);
                const bool taken = (d < dprev) || (d == dprev && j <= jprev);
                if (!taken && d < bd) { bd = d; bj = j; }
            }
            dprev = bd;
            jprev = bj;
        }
        const float* T = delta_tf + jprev * 16;
        xk0 = fmaf(T[0], tx, fmaf(T[1], ty, fmaf(T[2], tz, T[3])));
        xk1 = fmaf(T[4], tx, fmaf(T[5], ty, fmaf(T[6], tz, T[7])));
        xk2 = fmaf(T[8], tx, fmaf(T[9], ty, fmaf(T[10], tz, T[11])));
    } else {
        xk0 = tx; xk1 = ty; xk2 = tz;
    }

    float gx0 = 0.f, gx1 = 0.f, gx2 = 0.f;
    bool mask = (m < M);

    for (int step = -1; step < 8; ++step) {
        bool m3 = mask;
        if (step >= 0) {
            if (__ballot(mask) == 0ull) break;  // wave-local early exit
            if (m3) {
                const float u0 = STS(9), u1 = STS(10), u2 = STS(11);
                STS(12) = u0; STS(13) = u1; STS(14) = u2;  // dx = up
                xk0 += u0; xk1 += u1; xk2 += u2;
            }
        }
        const float cx0 = xk0, cx1 = xk1, cx2 = xk2;

        // ---- positional encoding, split by scale: sq computes sincos((1<<sq)*x)
        {
            const float f = (float)(1 << sq);
            float sx, cxv, sy, cyv, sz, czv;
            sincosf(f * cx0, &sx, &cxv);
            sincosf(f * cx1, &sy, &cyv);
            sincosf(f * cx2, &sz, &czv);
            if (sq == 0) { hq[0] = cx0; hq[1] = cx1; hq[2] = cx2; }
            const int sb = 3 + sq * 3;
            hq[sb + 0] = sx;  hq[sb + 1] = sy;  hq[sb + 2] = sz;
            hq[sb + 12] = cxv; hq[sb + 13] = cyv; hq[sb + 14] = czv;
            if (sq == 3) {
                hq[27] = 0.f; hq[28] = 0.f; hq[29] = 0.f; hq[30] = 0.f; hq[31] = 0.f;
            }
        }

        __builtin_amdgcn_s_setprio(1);
        layerM<32, 128>(W0p + 8 * cg, b0 + 8 * cg, hg, hwr);
        layerM<128, 128>(W1 + 8 * cg, b1 + 8 * cg, hg, hwr);
        layerM<128, 128>(W2 + 8 * cg, b2 + 8 * cg, hg, hwr);
        layerM<128, 128>(W3 + 8 * cg, b3 + 8 * cg, hg, hwr);

        // ---- output layer: lane (sq, p16) computes cols 8sq..8sq+8 of prob p16
        {
            v2f la[4];
            const float* bc = b4p + 8 * sq;
            const float4 bb0 = *(const float4*)(bc);
            const float4 bb1 = *(const float4*)(bc + 4);
            la[0] = mkv2(bb0.x, bb0.y); la[1] = mkv2(bb0.z, bb0.w);
            la[2] = mkv2(bb1.x, bb1.y); la[3] = mkv2(bb1.z, bb1.w);
            const float* Wc = W4p + 8 * sq;
#pragma unroll 2
            for (int kb = 0; kb < 32; ++kb) {
                const float4 h4 = *(const float4*)(hq + kb * 4);
#pragma unroll
                for (int r = 0; r < 4; ++r) {
                    const int k = kb * 4 + r;
                    const float4 w0 = *(const float4*)(Wc + k * 32);
                    const float4 w1 = *(const float4*)(Wc + k * 32 + 4);
                    const float hv = f4el(h4, r);
                    const v2f hh = mkv2(hv, hv);
                    la[0] = pkfma(hh, mkv2(w0.x, w0.y), la[0]);
                    la[1] = pkfma(hh, mkv2(w0.z, w0.w), la[1]);
                    la[2] = pkfma(hh, mkv2(w1.x, w1.y), la[2]);
                    la[3] = pkfma(hh, mkv2(w1.z, w1.w), la[3]);
                }
            }
            __builtin_amdgcn_s_setprio(0);
            float4 o0, o1;
            o0.x = la[0].x; o0.y = la[0].y; o0.z = la[1].x; o0.w = la[1].y;
            o1.x = la[2].x; o1.y = la[2].y; o1.z = la[3].x; o1.w = la[3].y;
            *(float4*)(hq + 8 * sq) = o0;
            *(float4*)(hq + 8 * sq + 4) = o1;
        }

        // ---- read 25 logits for my prob (dup x4)
        float l25[25];
        {
            const float4 r0 = *(const float4*)(hq + 0);
            const float4 r1 = *(const float4*)(hq + 4);
            const float4 r2 = *(const float4*)(hq + 8);
            const float4 r3 = *(const float4*)(hq + 12);
            const float4 r4 = *(const float4*)(hq + 16);
            const float4 r5 = *(const float4*)(hq + 20);
            l25[0] = r0.x; l25[1] = r0.y; l25[2] = r0.z; l25[3] = r0.w;
            l25[4] = r1.x; l25[5] = r1.y; l25[6] = r1.z; l25[7] = r1.w;
            l25[8] = r2.x; l25[9] = r2.y; l25[10] = r2.z; l25[11] = r2.w;
            l25[12] = r3.x; l25[13] = r3.y; l25[14] = r3.z; l25[15] = r3.w;
            l25[16] = r4.x; l25[17] = r4.y; l25[18] = r4.z; l25[19] = r4.w;
            l25[20] = r5.x; l25[21] = r5.y; l25[22] = r5.z; l25[23] = r5.w;
            l25[24] = hq[24];
        }

        // softmax(5 * logits) over 25 (duplicated across sq, identical)
        float zm = -3.4028235e38f;
#pragma unroll
        for (int j = 0; j < 25; ++j) {
            l25[j] = 5.0f * l25[j];
            zm = fmaxf(zm, l25[j]);
        }
        float ssum = 0.f;
#pragma unroll
        for (int j = 0; j < 25; ++j) {
            l25[j] = expf(l25[j] - zm);
            ssum += l25[j];
        }
        const float inv = 1.0f / ssum;

        float tf[12];
#pragma unroll
        for (int r = 0; r < 12; ++r) tf[r] = 0.f;
#pragma unroll
        for (int j = 0; j < 24; ++j) {
            const float wj = l25[j] * inv;
            const float* T = transforms + j * 16;
#pragma unroll
            for (int r = 0; r < 12; ++r) tf[r] = fmaf(wj, T[r], tf[r]);
        }
        {
            const float wj = l25[24] * inv;  // identity transform
            tf[0] += wj; tf[5] += wj; tf[10] += wj;
        }
        const float r0 = fmaf(tf[0], cx0, fmaf(tf[1], cx1, fmaf(tf[2], cx2, tf[3])));
        const float r1 = fmaf(tf[4], cx0, fmaf(tf[5], cx1, fmaf(tf[6], cx2, tf[7])));
        const float r2 = fmaf(tf[8], cx0, fmaf(tf[9], cx1, fmaf(tf[10], cx2, tf[11])));

        const float g0 = r0 - tx, g1 = r1 - ty, g2 = r2 - tz;

        if (step == -1) {
            gx0 = g0; gx1 = g1; gx2 = g2;
            const float gn = sqrtf(g0 * g0 + g1 * g1 + g2 * g2);
            STS(21) = gn;                                  // nopt
            STS(9) = -g0; STS(10) = -g1; STS(11) = -g2;    // up (Jinv = I)
            STS(18) = xk0; STS(19) = xk1; STS(20) = xk2;   // xo
            STS(22) = r0; STS(23) = r1; STS(24) = r2;      // rw cache
            STS(12) = 0.f; STS(13) = 0.f; STS(14) = 0.f;   // dx
            STS(15) = 0.f; STS(16) = 0.f; STS(17) = 0.f;   // dg
            STS(0) = 1.f; STS(1) = 0.f; STS(2) = 0.f;
            STS(3) = 0.f; STS(4) = 1.f; STS(5) = 0.f;
            STS(6) = 0.f; STS(7) = 0.f; STS(8) = 1.f;
        } else {
            float J00 = STS(0), J01 = STS(1), J02 = STS(2);
            float J10 = STS(3), J11 = STS(4), J12 = STS(5);
            float J20 = STS(6), J21 = STS(7), J22 = STS(8);
            const float dx0 = STS(12), dx1 = STS(13), dx2 = STS(14);
            float dg0 = STS(15), dg1 = STS(16), dg2 = STS(17);
            float nopt = STS(21);
            if (m3) {
                dg0 = g0 - gx0; dg1 = g1 - gx1; dg2 = g2 - gx2;
                gx0 += dg0; gx1 += dg1; gx2 += dg2;
                STS(15) = dg0; STS(16) = dg1; STS(17) = dg2;
            }
            const float gn = sqrtf(gx0 * gx0 + gx1 * gx1 + gx2 * gx2);
            const bool better = gn < nopt;
            if (better) {
                nopt = gn;
                STS(21) = gn;
                STS(18) = xk0; STS(19) = xk1; STS(20) = xk2;
                STS(22) = r0; STS(23) = r1; STS(24) = r2;  // rw at new xopt
            }
            mask = (nopt > 1e-5f) && (gn < 1.0f) && (m < M);

            const float v0 = dx0 * J00 + dx1 * J10 + dx2 * J20;
            const float v1 = dx0 * J01 + dx1 * J11 + dx2 * J21;
            const float v2 = dx0 * J02 + dx1 * J12 + dx2 * J22;
            const float Jd0 = J00 * dg0 + J01 * dg1 + J02 * dg2;
            const float Jd1 = J10 * dg0 + J11 * dg1 + J12 * dg2;
            const float Jd2 = J20 * dg0 + J21 * dg1 + J22 * dg2;
            const float a0 = dx0 - Jd0, a1 = dx1 - Jd1, a2 = dx2 - Jd2;
            float bden = v0 * dg0 + v1 * dg1 + v2 * dg2;
            bden += (bden >= 0.f) ? 1e-6f : -1e-6f;
            if (mask) {
                const float q0 = a0 / bden, q1 = a1 / bden, q2 = a2 / bden;
                J00 = fmaf(q0, v0, J00); J01 = fmaf(q0, v1, J01); J02 = fmaf(q0, v2, J02);
                J10 = fmaf(q1, v0, J10); J11 = fmaf(q1, v1, J11); J12 = fmaf(q1, v2, J12);
                J20 = fmaf(q2, v0, J20); J21 = fmaf(q2, v1, J21); J22 = fmaf(q2, v2, J22);
                STS(0) = J00; STS(1) = J01; STS(2) = J02;
                STS(3) = J10; STS(4) = J11; STS(5) = J12;
                STS(6) = J20; STS(7) = J21; STS(8) = J22;
            }
            if (m3) {
                STS(9) = -(J00 * gx0 + J01 * gx1 + J02 * gx2);
                STS(10) = -(J10 * gx0 + J11 * gx1 + J12 * gx2);
                STS(11) = -(J20 * gx0 + J21 * gx1 + J22 * gx2);
            }
        }
    }

    // ---- epilogue: outputs come entirely from cached state (no final eval)
    if (sq == 0 && m < M) {
        const float nopt = STS(21);
        out[(size_t)m * 3 + 0] = STS(22);
        out[(size_t)m * 3 + 1] = STS(23);
        out[(size_t)m * 3 + 2] = STS(24);
        float* xopt_out = out + (size_t)M * 3;
        xopt_out[(size_t)m * 3 + 0] = STS(18);
        xopt_out[(size_t)m * 3 + 1] = STS(19);
        xopt_out[(size_t)m * 3 + 2] = STS(20);
        out[(size_t)M * 6 + m] = nopt;
        out[(size_t)M * 7 + m] = (nopt < 1e-5f) ? 1.0f : 0.0f;
    }
#undef STS
}

extern "C" void kernel_launch(void* const* d_in, const int* in_sizes, int n_in,
                              void* d_out, int out_size, void* d_ws, size_t ws_size,
                              hipStream_t stream) {
    const float* x = (const float*)d_in[0];
    const float* bone_pts = (const float*)d_in[1];
    const float* transforms = (const float*)d_in[2];
    const float* delta_tf = (const float*)d_in[3];
    const float* W0 = (const float*)d_in[4];
    const float* b0 = (const float*)d_in[5];
    const float* W1 = (const float*)d_in[6];
    const float* b1 = (const float*)d_in[7];
    const float* W2 = (const float*)d_in[8];
    const float* b2 = (const float*)d_in[9];
    const float* W3 = (const float*)d_in[10];
    const float* b3 = (const float*)d_in[11];
    const float* W4 = (const float*)d_in[12];
    const float* b4 = (const float*)d_in[13];
    float* out = (float*)d_out;

    float* W0p = (float*)d_ws;    // 32*128
    float* W4p = W0p + 32 * 128;  // 128*32
    float* b4p = W4p + 128 * 32;  // 32

    prep_kernel<<<16, 256, 0, stream>>>(W0, W4, b4, W0p, W4p, b4p);

    const int Npts = in_sizes[0] / 3;
    const int M = Npts * 6;
    const int blocks = (M + PPB - 1) / PPB;
    snarf_kernel<<<blocks, BLOCK, 0, stream>>>(
        x, bone_pts, transforms, delta_tf, W0p, b0, W1, b1, W2, b2, W3, b3,
        W4p, b4p, out, Npts);
}

// Round 12
// 1747.266 us; speedup vs baseline: 10.8509x; 1.1602x over previous
//
#include <hip/hip_runtime.h>
#include <math.h>

#define BLOCK 256
#define PPB 64     // problems per block (16 per wave)
#define HP 132     // h row stride per prob
#define WCOLS 2136 // per-wave h region floats (16*132 + 3*8 swizzle pad)
#define NTILES 56  // 4 (W0) + 16*3 (W1..3) + 4 (W4) tiles of 1024 floats

typedef float v2f __attribute__((ext_vector_type(2)));

__device__ __forceinline__ v2f mkv2(float a, float b) {
    v2f r; r.x = a; r.y = b; return r;
}
__device__ __forceinline__ v2f pkfma(v2f a, v2f b, v2f c) {
#if __has_builtin(__builtin_elementwise_fma)
    return __builtin_elementwise_fma(a, b, c);
#else
    return mkv2(fmaf(a.x, b.x, c.x), fmaf(a.y, b.y, c.y));
#endif
}
__device__ __forceinline__ float f4el(const float4& v, int r) {
    return (r == 0) ? v.x : (r == 1) ? v.y : (r == 2) ? v.z : v.w;
}
__device__ __forceinline__ int col_base(int p) { return p * HP + ((p >> 2) << 3); }

// prep: write all weights as 56 contiguous tiles of 1024 floats.
// tiles 0..3   : W0 rows 8t..8t+7 (zero-padded past row 26), 128 cols
// tiles 4..19  : W1 rows 8(t-4)..   ; 20..35: W2 ; 36..51: W3
// tiles 52..55 : W4 rows 32(t-52).., 32 cols (zero-padded past col 24)
// In-tile layout (main): word = r*128 + half*64 + cg*4 + jl, col = 8cg+4*half+jl
//   -> lane reads (fixed r): addr 4cg mod 32 -> 2 lanes/bank-quad = conflict-free
// In-tile layout (W4): word = r*32 + half*16 + sq*4 + jl, col = 8sq+4*half+jl
__global__ void prep_kernel(const float* __restrict__ W0, const float* __restrict__ W1,
                            const float* __restrict__ W2, const float* __restrict__ W3,
                            const float* __restrict__ W4, const float* __restrict__ b4,
                            float* __restrict__ Wt, float* __restrict__ b4p) {
    const int d = blockIdx.x * blockDim.x + threadIdx.x;
    if (d < NTILES * 1024) {
        const int t = d >> 10, w = d & 1023;
        float v;
        if (t < 52) {
            const int r = w >> 7, rem = w & 127;
            const int half = rem >> 6, q = (rem >> 2) & 15, jl = rem & 3;
            const int col = q * 8 + half * 4 + jl;
            if (t < 4)       { const int k = t * 8 + r;        v = (k < 27) ? W0[k * 128 + col] : 0.f; }
            else if (t < 20) { const int k = (t - 4) * 8 + r;  v = W1[k * 128 + col]; }
            else if (t < 36) { const int k = (t - 20) * 8 + r; v = W2[k * 128 + col]; }
            else             { const int k = (t - 36) * 8 + r; v = W3[k * 128 + col]; }
        } else {
            const int r = w >> 5, rem = w & 31;
            const int half = (rem >> 4) & 1, s = (rem >> 2) & 3, jl = rem & 3;
            const int col = s * 8 + half * 4 + jl;
            const int k = (t - 52) * 32 + r;
            v = (col < 25) ? W4[k * 25 + col] : 0.f;
        }
        Wt[d] = v;
    }
    if (d < 32) b4p[d] = (d < 25) ? b4[d] : 0.f;
}

// 4-row FMA batch, weights from LDS tile (rows r0..r0+3), h from LDS
__device__ __forceinline__ void batch4(const float* wt, int r0, int cg,
                                       const float* hg, int k0,
                                       v2f* __restrict__ acc) {
    float4 h4[4];
#pragma unroll
    for (int p = 0; p < 4; ++p) h4[p] = *(const float4*)(hg + p * HP + k0);
    float4 w0[4], w1[4];
#pragma unroll
    for (int r = 0; r < 4; ++r) {
        w0[r] = *(const float4*)(wt + (r0 + r) * 128 + cg * 4);
        w1[r] = *(const float4*)(wt + (r0 + r) * 128 + 64 + cg * 4);
    }
#pragma unroll
    for (int r = 0; r < 4; ++r) {
        const v2f wa = mkv2(w0[r].x, w0[r].y), wb2 = mkv2(w0[r].z, w0[r].w);
        const v2f wc = mkv2(w1[r].x, w1[r].y), wd = mkv2(w1[r].z, w1[r].w);
#pragma unroll
        for (int p = 0; p < 4; ++p) {
            const float hv = f4el(h4[p], r);
            const v2f hh = mkv2(hv, hv);
            acc[p * 4 + 0] = pkfma(hh, wa, acc[p * 4 + 0]);
            acc[p * 4 + 1] = pkfma(hh, wb2, acc[p * 4 + 1]);
            acc[p * 4 + 2] = pkfma(hh, wc, acc[p * 4 + 2]);
            acc[p * 4 + 3] = pkfma(hh, wd, acc[p * 4 + 3]);
        }
    }
}

// LDS solver state slots: 0..8 J, 9..11 up, 12..14 dx, 15..17 dg, 18..20 xo,
// 21 nopt, 22..24 rw
__global__ __launch_bounds__(BLOCK)
__attribute__((amdgpu_num_vgpr(128))) void snarf_kernel(
    const float* __restrict__ xin, const float* __restrict__ bone_pts,
    const float* __restrict__ transforms, const float* __restrict__ delta_tf,
    const float* __restrict__ Wt, const float* __restrict__ b0,
    const float* __restrict__ b1, const float* __restrict__ b2,
    const float* __restrict__ b3, const float* __restrict__ b4p,
    float* __restrict__ out, int Npts) {
    __shared__ float hL[4 * WCOLS];   // 34176 B swizzled h[prob][k]
    __shared__ float stL[25 * PPB];   // 6400 B solver state
    __shared__ float wb[2][1024];     // 8192 B weight tile double-buffer
    __shared__ int flags[4];          // block-exit flags (total 48784 B)
    const int tid = threadIdx.x;
    const int wid = tid >> 6;
    const int lane = tid & 63;
    const int p16 = lane & 15;
    const int sq = lane >> 4;
    const int cg = lane >> 2;
    const int gg = lane & 3;
    const int M = Npts * 6;
    const int m = blockIdx.x * PPB + wid * 16 + p16;
    const int mc = (m < M) ? m : (M - 1);
    const int n = mc / 6;
    const int i = mc - n * 6;

    float* hWv = &hL[wid * WCOLS];
    const float* hg = hWv + gg * 536;
    float* hwr = hWv + gg * 536 + 8 * cg;
    float* hq = hWv + col_base(p16);
    volatile float* st = &stL[wid * 16 + p16];
#define STS(idx) st[(idx) * PPB]

    const float tx = xin[n * 3 + 0], ty = xin[n * 3 + 1], tz = xin[n * 3 + 2];

    // ---- init candidate (duplicated across sq; bitwise identical)
    float xk0, xk1, xk2;
    if (i < 5) {
        float dprev = -1.0f;
        int jprev = -1;
        for (int r = 0; r <= i; ++r) {
            float bd = 3.4028235e38f;
            int bj = 0;
            for (int j = 0; j < 24; ++j) {
                const float ax = tx - bone_pts[j * 3 + 0];
                const float ay = ty - bone_pts[j * 3 + 1];
                const float az = tz - bone_pts[j * 3 + 2];
                const float d = sqrtf(ax * ax + ay * ay + az * az);
                const bool taken = (d < dprev) || (d == dprev && j <= jprev);
                if (!taken && d < bd) { bd = d; bj = j; }
            }
            dprev = bd;
            jprev = bj;
        }
        const float* T = delta_tf + jprev * 16;
        xk0 = fmaf(T[0], tx, fmaf(T[1], ty, fmaf(T[2], tz, T[3])));
        xk1 = fmaf(T[4], tx, fmaf(T[5], ty, fmaf(T[6], tz, T[7])));
        xk2 = fmaf(T[8], tx, fmaf(T[9], ty, fmaf(T[10], tz, T[11])));
    } else {
        xk0 = tx; xk1 = ty; xk2 = tz;
    }

    float gx0 = 0.f, gx1 = 0.f, gx2 = 0.f;
    bool mask = (m < M);

    // stage tile 0 into buf 0
    int cur = 0;
    *(float4*)(&wb[0][0] + tid * 4) = *(const float4*)(Wt + tid * 4);
    __syncthreads();

    for (int step = -1; step < 8; ++step) {
        bool m3 = mask;
        if (step >= 0) {
            // flags were written at end of previous iteration; barrier makes visible
            __syncthreads();
            if ((flags[0] | flags[1] | flags[2] | flags[3]) == 0) break;
            if (m3) {
                const float u0 = STS(9), u1 = STS(10), u2 = STS(11);
                STS(12) = u0; STS(13) = u1; STS(14) = u2;
                xk0 += u0; xk1 += u1; xk2 += u2;
            }
        }
        const float cx0 = xk0, cx1 = xk1, cx2 = xk2;

        // ---- positional encoding, split by scale (sq owns scale 1<<sq)
        {
            const float f = (float)(1 << sq);
            float sx, cxv, sy, cyv, sz, czv;
            sincosf(f * cx0, &sx, &cxv);
            sincosf(f * cx1, &sy, &cyv);
            sincosf(f * cx2, &sz, &czv);
            if (sq == 0) { hq[0] = cx0; hq[1] = cx1; hq[2] = cx2; }
            const int sb = 3 + sq * 3;
            hq[sb + 0] = sx;  hq[sb + 1] = sy;  hq[sb + 2] = sz;
            hq[sb + 12] = cxv; hq[sb + 13] = cyv; hq[sb + 14] = czv;
            if (sq == 3) {
                hq[27] = 0.f; hq[28] = 0.f; hq[29] = 0.f; hq[30] = 0.f; hq[31] = 0.f;
            }
        }

        __builtin_amdgcn_s_setprio(1);
        // ---- 4 main layers from LDS tiles (tiles 0..51)
#pragma unroll 1
        for (int L = 0; L < 4; ++L) {
            const int tbase = (L == 0) ? 0 : (4 + (L - 1) * 16);
            const int NT = (L == 0) ? 4 : 16;
            const float* bc = ((L == 0) ? b0 : (L == 1) ? b1 : (L == 2) ? b2 : b3) + 8 * cg;
            v2f acc[16];
            {
                const float4 b0v = *(const float4*)(bc);
                const float4 b1v = *(const float4*)(bc + 4);
#pragma unroll
                for (int p = 0; p < 4; ++p) {
                    acc[p * 4 + 0] = mkv2(b0v.x, b0v.y);
                    acc[p * 4 + 1] = mkv2(b0v.z, b0v.w);
                    acc[p * 4 + 2] = mkv2(b1v.x, b1v.y);
                    acc[p * 4 + 3] = mkv2(b1v.z, b1v.w);
                }
            }
#pragma unroll 1
            for (int t = 0; t < NT; ++t) {
                // T14 async-stage: load next tile early, write to LDS late
                const float4 stg = *(const float4*)(Wt + (tbase + t + 1) * 1024 + tid * 4);
                batch4(&wb[cur][0], 0, cg, hg, t * 8, acc);
                batch4(&wb[cur][0], 4, cg, hg, t * 8 + 4, acc);
                *(float4*)(&wb[cur ^ 1][0] + tid * 4) = stg;
                __syncthreads();
                cur ^= 1;
            }
#pragma unroll
            for (int p = 0; p < 4; ++p) {
                float4 o0, o1;
                o0.x = fmaxf(acc[p * 4 + 0].x, 0.f); o0.y = fmaxf(acc[p * 4 + 0].y, 0.f);
                o0.z = fmaxf(acc[p * 4 + 1].x, 0.f); o0.w = fmaxf(acc[p * 4 + 1].y, 0.f);
                o1.x = fmaxf(acc[p * 4 + 2].x, 0.f); o1.y = fmaxf(acc[p * 4 + 2].y, 0.f);
                o1.z = fmaxf(acc[p * 4 + 3].x, 0.f); o1.w = fmaxf(acc[p * 4 + 3].y, 0.f);
                *(float4*)(hwr + p * HP) = o0;
                *(float4*)(hwr + p * HP + 4) = o1;
            }
        }

        // ---- output layer: tiles 52..55 (32 rows x 32 cols each)
        {
            v2f la[4];
            const float4 bb0 = *(const float4*)(b4p + 8 * sq);
            const float4 bb1 = *(const float4*)(b4p + 8 * sq + 4);
            la[0] = mkv2(bb0.x, bb0.y); la[1] = mkv2(bb0.z, bb0.w);
            la[2] = mkv2(bb1.x, bb1.y); la[3] = mkv2(bb1.z, bb1.w);
#pragma unroll 1
            for (int t = 0; t < 4; ++t) {
                const int nt = (t < 3) ? (53 + t) : 0;  // wrap: last stages tile 0
                const float4 stg = *(const float4*)(Wt + nt * 1024 + tid * 4);
                const float* wt = &wb[cur][0];
#pragma unroll 2
                for (int kb = 0; kb < 8; ++kb) {
                    const float4 h4 = *(const float4*)(hq + t * 32 + kb * 4);
#pragma unroll
                    for (int r = 0; r < 4; ++r) {
                        const float4 w0 = *(const float4*)(wt + (kb * 4 + r) * 32 + sq * 4);
                        const float4 w1 = *(const float4*)(wt + (kb * 4 + r) * 32 + 16 + sq * 4);
                        const float hv = f4el(h4, r);
                        const v2f hh = mkv2(hv, hv);
                        la[0] = pkfma(hh, mkv2(w0.x, w0.y), la[0]);
                        la[1] = pkfma(hh, mkv2(w0.z, w0.w), la[1]);
                        la[2] = pkfma(hh, mkv2(w1.x, w1.y), la[2]);
                        la[3] = pkfma(hh, mkv2(w1.z, w1.w), la[3]);
                    }
                }
                *(float4*)(&wb[cur ^ 1][0] + tid * 4) = stg;
                __syncthreads();
                cur ^= 1;
            }
            __builtin_amdgcn_s_setprio(0);
            float4 o0, o1;
            o0.x = la[0].x; o0.y = la[0].y; o0.z = la[1].x; o0.w = la[1].y;
            o1.x = la[2].x; o1.y = la[2].y; o1.z = la[3].x; o1.w = la[3].y;
            *(float4*)(hq + 8 * sq) = o0;
            *(float4*)(hq + 8 * sq + 4) = o1;
        }

        // ---- read 25 logits (dup x4)
        float l25[25];
        {
            const float4 r0 = *(const float4*)(hq + 0);
            const float4 r1 = *(const float4*)(hq + 4);
            const float4 r2 = *(const float4*)(hq + 8);
            const float4 r3 = *(const float4*)(hq + 12);
            const float4 r4 = *(const float4*)(hq + 16);
            const float4 r5 = *(const float4*)(hq + 20);
            l25[0] = r0.x; l25[1] = r0.y; l25[2] = r0.z; l25[3] = r0.w;
            l25[4] = r1.x; l25[5] = r1.y; l25[6] = r1.z; l25[7] = r1.w;
            l25[8] = r2.x; l25[9] = r2.y; l25[10] = r2.z; l25[11] = r2.w;
            l25[12] = r3.x; l25[13] = r3.y; l25[14] = r3.z; l25[15] = r3.w;
            l25[16] = r4.x; l25[17] = r4.y; l25[18] = r4.z; l25[19] = r4.w;
            l25[20] = r5.x; l25[21] = r5.y; l25[22] = r5.z; l25[23] = r5.w;
            l25[24] = hq[24];
        }

        // softmax(5 * logits) over 25
        float zm = -3.4028235e38f;
#pragma unroll
        for (int j = 0; j < 25; ++j) {
            l25[j] = 5.0f * l25[j];
            zm = fmaxf(zm, l25[j]);
        }
        float ssum = 0.f;
#pragma unroll
        for (int j = 0; j < 25; ++j) {
            l25[j] = expf(l25[j] - zm);
            ssum += l25[j];
        }
        const float inv = 1.0f / ssum;

        float tf[12];
#pragma unroll
        for (int r = 0; r < 12; ++r) tf[r] = 0.f;
#pragma unroll
        for (int j = 0; j < 24; ++j) {
            const float wj = l25[j] * inv;
            const float* T = transforms + j * 16;
#pragma unroll
            for (int r = 0; r < 12; ++r) tf[r] = fmaf(wj, T[r], tf[r]);
        }
        {
            const float wj = l25[24] * inv;
            tf[0] += wj; tf[5] += wj; tf[10] += wj;
        }
        const float r0 = fmaf(tf[0], cx0, fmaf(tf[1], cx1, fmaf(tf[2], cx2, tf[3])));
        const float r1 = fmaf(tf[4], cx0, fmaf(tf[5], cx1, fmaf(tf[6], cx2, tf[7])));
        const float r2 = fmaf(tf[8], cx0, fmaf(tf[9], cx1, fmaf(tf[10], cx2, tf[11])));

        const float g0 = r0 - tx, g1 = r1 - ty, g2 = r2 - tz;

        if (step == -1) {
            gx0 = g0; gx1 = g1; gx2 = g2;
            const float gn = sqrtf(g0 * g0 + g1 * g1 + g2 * g2);
            STS(21) = gn;
            STS(9) = -g0; STS(10) = -g1; STS(11) = -g2;
            STS(18) = xk0; STS(19) = xk1; STS(20) = xk2;
            STS(22) = r0; STS(23) = r1; STS(24) = r2;
            STS(12) = 0.f; STS(13) = 0.f; STS(14) = 0.f;
            STS(15) = 0.f; STS(16) = 0.f; STS(17) = 0.f;
            STS(0) = 1.f; STS(1) = 0.f; STS(2) = 0.f;
            STS(3) = 0.f; STS(4) = 1.f; STS(5) = 0.f;
            STS(6) = 0.f; STS(7) = 0.f; STS(8) = 1.f;
        } else {
            float J00 = STS(0), J01 = STS(1), J02 = STS(2);
            float J10 = STS(3), J11 = STS(4), J12 = STS(5);
            float J20 = STS(6), J21 = STS(7), J22 = STS(8);
            const float dx0 = STS(12), dx1 = STS(13), dx2 = STS(14);
            float dg0 = STS(15), dg1 = STS(16), dg2 = STS(17);
            float nopt = STS(21);
            if (m3) {
                dg0 = g0 - gx0; dg1 = g1 - gx1; dg2 = g2 - gx2;
                gx0 += dg0; gx1 += dg1; gx2 += dg2;
                STS(15) = dg0; STS(16) = dg1; STS(17) = dg2;
            }
            const float gn = sqrtf(gx0 * gx0 + gx1 * gx1 + gx2 * gx2);
            const bool better = gn < nopt;
            if (better) {
                nopt = gn;
                STS(21) = gn;
                STS(18) = xk0; STS(19) = xk1; STS(20) = xk2;
                STS(22) = r0; STS(23) = r1; STS(24) = r2;
            }
            mask = (nopt > 1e-5f) && (gn < 1.0f) && (m < M);

            const float v0 = dx0 * J00 + dx1 * J10 + dx2 * J20;
            const float v1 = dx0 * J01 + dx1 * J11 + dx2 * J21;
            const float v2 = dx0 * J02 + dx1 * J12 + dx2 * J22;
            const float Jd0 = J00 * dg0 + J01 * dg1 + J02 * dg2;
            const float Jd1 = J10 * dg0 + J11 * dg1 + J12 * dg2;
            const float Jd2 = J20 * dg0 + J21 * dg1 + J22 * dg2;
            const float a0 = dx0 - Jd0, a1 = dx1 - Jd1, a2 = dx2 - Jd2;
            float bden = v0 * dg0 + v1 * dg1 + v2 * dg2;
            bden += (bden >= 0.f) ? 1e-6f : -1e-6f;
            if (mask) {
                const float q0 = a0 / bden, q1 = a1 / bden, q2 = a2 / bden;
                J00 = fmaf(q0, v0, J00); J01 = fmaf(q0, v1, J01); J02 = fmaf(q0, v2, J02);
                J10 = fmaf(q1, v0, J10); J11 = fmaf(q1, v1, J11); J12 = fmaf(q1, v2, J12);
                J20 = fmaf(q2, v0, J20); J21 = fmaf(q2, v1, J21); J22 = fmaf(q2, v2, J22);
                STS(0) = J00; STS(1) = J01; STS(2) = J02;
                STS(3) = J10; STS(4) = J11; STS(5) = J12;
                STS(6) = J20; STS(7) = J21; STS(8) = J22;
            }
            if (m3) {
                STS(9) = -(J00 * gx0 + J01 * gx1 + J02 * gx2);
                STS(10) = -(J10 * gx0 + J11 * gx1 + J12 * gx2);
                STS(11) = -(J20 * gx0 + J21 * gx1 + J22 * gx2);
            }
        }
        // block-exit flags (read after barrier at next loop top)
        {
            const unsigned long long b = __ballot(mask);
            if (lane == 0) flags[wid] = (b != 0ull) ? 1 : 0;
        }
    }

    // ---- epilogue: all outputs from cached state
    if (sq == 0 && m < M) {
        const float nopt = STS(21);
        out[(size_t)m * 3 + 0] = STS(22);
        out[(size_t)m * 3 + 1] = STS(23);
        out[(size_t)m * 3 + 2] = STS(24);
        float* xopt_out = out + (size_t)M * 3;
        xopt_out[(size_t)m * 3 + 0] = STS(18);
        xopt_out[(size_t)m * 3 + 1] = STS(19);
        xopt_out[(size_t)m * 3 + 2] = STS(20);
        out[(size_t)M * 6 + m] = nopt;
        out[(size_t)M * 7 + m] = (nopt < 1e-5f) ? 1.0f : 0.0f;
    }
#undef STS
}

extern "C" void kernel_launch(void* const* d_in, const int* in_sizes, int n_in,
                              void* d_out, int out_size, void* d_ws, size_t ws_size,
                              hipStream_t stream) {
    const float* x = (const float*)d_in[0];
    const float* bone_pts = (const float*)d_in[1];
    const float* transforms = (const float*)d_in[2];
    const float* delta_tf = (const float*)d_in[3];
    const float* W0 = (const float*)d_in[4];
    const float* b0 = (const float*)d_in[5];
    const float* W1 = (const float*)d_in[6];
    const float* b1 = (const float*)d_in[7];
    const float* W2 = (const float*)d_in[8];
    const float* b2 = (const float*)d_in[9];
    const float* W3 = (const float*)d_in[10];
    const float* b3 = (const float*)d_in[11];
    const float* W4 = (const float*)d_in[12];
    const float* b4 = (const float*)d_in[13];
    float* out = (float*)d_out;

    float* Wt = (float*)d_ws;              // 56*1024 floats (tiled weights)
    float* b4p = Wt + NTILES * 1024;       // 32 floats

    prep_kernel<<<(NTILES * 1024 + 255) / 256, 256, 0, stream>>>(
        W0, W1, W2, W3, W4, b4, Wt, b4p);

    const int Npts = in_sizes[0] / 3;
    const int M = Npts * 6;
    const int blocks = (M + PPB - 1) / PPB;
    snarf_kernel<<<blocks, BLOCK, 0, stream>>>(
        x, bone_pts, transforms, delta_tf, Wt, b0, b1, b2, b3, b4p, out, Npts);
}